// Round 3
// baseline (277.614 us; speedup 1.0000x reference)
//
#include <hip/hip_runtime.h>
#include <math.h>

// Fused SNN: conv1d(64-tap over C, pad 32) + BN + PLIF scan over T + mean + FC.
// x: (1024, 80, 500) f32. One block per sample n. 256 threads = 4 waves.
// R3 = R1's proven-deterministic LDS-staged skeleton + two occupancy fixes:
//   - xs has NO zero-pad rows (80x64, 20.5 KB); FIR boundary taps use
//     per-lane predicated LDS reads (exec-masked ds_read, deterministic).
//   - 256 threads, 21 channels/wave (4*21=84 covers 81), LDS ~42 KB
//     -> 3 blocks/CU so FIR of other blocks hides scan/stage phases.
// Per 64-col t-chunk: stage x[n,:,chunk] -> xs | barrier | register FIR
// (21 accs, 21-reg sliding window, 64 taps unrolled, weights via LDS
// broadcast) -> ybuf | barrier | PLIF scan (lanes 0..80, in registers)
// | barrier. Last chunk: 52 cols; xs cols 52..63 stale (never read by scan).

#define NTHREADS 256
#define CPW      21
#define TC       64
#define YSTRIDE  65       // +1 pad: conflict-free column reads in scan
#define NCHUNK   8        // 7*64 + 52 = 500

__global__ __launch_bounds__(NTHREADS, 3)
void snn_fused_kernel(const float* __restrict__ x,
                      const float* __restrict__ conv_w,
                      const float* __restrict__ conv_b,
                      const float* __restrict__ bn_gamma,
                      const float* __restrict__ bn_beta,
                      const float* __restrict__ bn_mean,
                      const float* __restrict__ bn_var,
                      const float* __restrict__ plif_w,
                      const float* __restrict__ fc_w,
                      const float* __restrict__ fc_b,
                      float* __restrict__ out)
{
    __shared__ float xs[80 * TC];          // 20480 B
    __shared__ float ybuf[81 * YSTRIDE];   // 21060 B
    __shared__ float wsh[64];
    __shared__ float feat[81];

    const int tid  = threadIdx.x;
    const int n    = blockIdx.x;
    const int lane = tid & 63;             // t column within chunk
    const int co0  = (tid >> 6) * CPW;     // wave's first output channel

    if (tid < 64) wsh[tid] = conv_w[tid];

    // per-lane scan constants (lanes 0..80 = channels)
    const float decay = 1.0f / (1.0f + expf(-plif_w[0]));
    float v = 0.0f, cnt = 0.0f;
    float inv_c = 0.0f, bb_c = 0.0f;
    if (tid < 81) {
        inv_c = bn_gamma[tid] * rsqrtf(bn_var[tid] + 1e-5f);
        bb_c  = conv_b[0] * inv_c + bn_beta[tid] - bn_mean[tid] * inv_c;
    }

    const float* xn = x + (size_t)n * (80 * 500);

    __syncthreads();

    for (int chunk = 0; chunk < NCHUNK; ++chunk) {
        const int t0 = chunk * TC;

        // ---- stage x[n, :, t0:t0+tcols] -> xs (float4, coalesced) ----
        if (chunk < NCHUNK - 1) {
            #pragma unroll
            for (int it = 0; it < 5; ++it) {               // 80*16/256 = 5
                const int i  = it * NTHREADS + tid;
                const int c  = i >> 4;
                const int t4 = i & 15;
                float4 v4 = *reinterpret_cast<const float4*>(xn + c * 500 + t0 + t4 * 4);
                *reinterpret_cast<float4*>(&xs[c * TC + t4 * 4]) = v4;
            }
        } else {
            for (int i = tid; i < 80 * 13; i += NTHREADS) { // 52 cols
                const int c  = i / 13;
                const int t4 = i - c * 13;
                float4 v4 = *reinterpret_cast<const float4*>(xn + c * 500 + t0 + t4 * 4);
                *reinterpret_cast<float4*>(&xs[c * TC + t4 * 4]) = v4;
            }
        }
        __syncthreads();

        // ---- register FIR: y[co0+r][lane] = sum_k w[k]*x[co0+r+k-32, lane] ----
        {
            float acc[CPW];
            float win[CPW];                 // win[(k+r)%CPW] = row co0+k+r-32
            #pragma unroll
            for (int r = 0; r < CPW; ++r) acc[r] = 0.0f;
            const int row0 = co0 - 32;
            #pragma unroll
            for (int m = 0; m < CPW - 1; ++m) {
                const int row = row0 + m;
                win[m] = ((unsigned)row < 80u) ? xs[row * TC + lane] : 0.0f;
            }
            #pragma unroll
            for (int k = 0; k < 64; ++k) {
                const int row = row0 + k + (CPW - 1);
                win[(k + CPW - 1) % CPW] =
                    ((unsigned)row < 80u) ? xs[row * TC + lane] : 0.0f;
                const float wk = wsh[k];                   // LDS broadcast
                #pragma unroll
                for (int r = 0; r < CPW; ++r)
                    acc[r] = fmaf(wk, win[(k + r) % CPW], acc[r]);
            }
            #pragma unroll
            for (int r = 0; r < CPW; ++r) {
                const int co = co0 + r;
                if (co < 81) ybuf[co * YSTRIDE + lane] = acc[r];
            }
        }
        __syncthreads();

        // ---- PLIF scan: lane c advances tcols steps ----
        const int tcols = (chunk == NCHUNK - 1) ? 52 : 64;  // 500 = 7*64+52
        if (tid < 81) {
            const float* yrow = &ybuf[tid * YSTRIDE];
            #pragma unroll 4
            for (int t = 0; t < tcols; ++t) {
                const float xt = fmaf(yrow[t], inv_c, bb_c);   // BN(conv+bias)
                v = fmaf(xt - v, decay, v);                    // v += (x-v)*decay
                const bool s = (v >= 1.0f);
                cnt += s ? 1.0f : 0.0f;
                v = s ? 0.0f : v;
            }
        }
        __syncthreads();
    }

    if (tid < 81) feat[tid] = cnt * (1.0f / 500.0f);
    __syncthreads();

    if (tid < 3) {
        float o = fc_b[tid];
        #pragma unroll 3
        for (int c = 0; c < 81; ++c)
            o = fmaf(feat[c], fc_w[tid * 81 + c], o);
        out[n * 3 + tid] = o;
    }
}

extern "C" void kernel_launch(void* const* d_in, const int* in_sizes, int n_in,
                              void* d_out, int out_size, void* d_ws, size_t ws_size,
                              hipStream_t stream)
{
    const float* x        = (const float*)d_in[0];
    const float* conv_w   = (const float*)d_in[1];
    const float* conv_b   = (const float*)d_in[2];
    const float* bn_gamma = (const float*)d_in[3];
    const float* bn_beta  = (const float*)d_in[4];
    const float* bn_mean  = (const float*)d_in[5];
    const float* bn_var   = (const float*)d_in[6];
    const float* plif_w   = (const float*)d_in[7];
    const float* fc_w     = (const float*)d_in[8];
    const float* fc_b     = (const float*)d_in[9];
    float* out            = (float*)d_out;

    snn_fused_kernel<<<1024, NTHREADS, 0, stream>>>(
        x, conv_w, conv_b, bn_gamma, bn_beta, bn_mean, bn_var,
        plif_w, fc_w, fc_b, out);
}

// Round 4
// 240.846 us; speedup vs baseline: 1.1527x; 1.1527x over previous
//
#include <hip/hip_runtime.h>
#include <math.h>

// Fused SNN: conv1d(64-tap over C, pad 32) + BN + PLIF scan over T + mean + FC.
// x: (1024, 80, 500) f32. One block per sample n. 384 threads = 6 waves.
// Wave w owns channels co0=14*w .. co0+13 (84 covers 81). CPW=14 is the
// PROVEN full-unroll size (R1: 896-FMA body, VGPR=80, zero scratch);
// CPW=21 (R3) spilled the sliding window to scratch (54 MB HBM writes).
// xs has no zero-pad rows; FIR boundary taps are per-lane predicated LDS
// reads. T14 async-stage: next chunk's x is loaded to registers at the top
// of the chunk (hidden under FIR) and written to xs during the scan phase
// (xs readers are past the barrier; scan only touches ybuf).
// LDS ~42 KB -> 3 blocks/CU.

#define NTHREADS 384
#define CPW      14
#define TC       64
#define YSTRIDE  65       // +1 pad: conflict-free column reads in scan
#define NCHUNK   8        // 7*64 + 52 = 500

__global__ __launch_bounds__(NTHREADS)
void snn_fused_kernel(const float* __restrict__ x,
                      const float* __restrict__ conv_w,
                      const float* __restrict__ conv_b,
                      const float* __restrict__ bn_gamma,
                      const float* __restrict__ bn_beta,
                      const float* __restrict__ bn_mean,
                      const float* __restrict__ bn_var,
                      const float* __restrict__ plif_w,
                      const float* __restrict__ fc_w,
                      const float* __restrict__ fc_b,
                      float* __restrict__ out)
{
    __shared__ float xs[80 * TC];          // 20480 B
    __shared__ float ybuf[81 * YSTRIDE];   // 21060 B
    __shared__ float wsh[64];
    __shared__ float feat[81];

    const int tid  = threadIdx.x;
    const int n    = blockIdx.x;
    const int lane = tid & 63;             // t column within chunk
    const int co0  = (tid >> 6) * CPW;     // wave's first output channel

    if (tid < 64) wsh[tid] = conv_w[tid];

    // per-lane scan constants (lanes 0..80 = channels)
    const float decay = 1.0f / (1.0f + expf(-plif_w[0]));
    float v = 0.0f, cnt = 0.0f;
    float inv_c = 0.0f, bb_c = 0.0f;
    if (tid < 81) {
        inv_c = bn_gamma[tid] * rsqrtf(bn_var[tid] + 1e-5f);
        bb_c  = conv_b[0] * inv_c + bn_beta[tid] - bn_mean[tid] * inv_c;
    }

    const float* xn = x + (size_t)n * (80 * 500);

    // ---- prefetch + stage chunk 0 ----  (80 rows * 16 float4 = 1280 items)
    float4 pf[4];
    #pragma unroll
    for (int it = 0; it < 4; ++it) {
        const int i = it * NTHREADS + tid;
        if (i < 1280) {
            const int c  = i >> 4;
            const int t4 = i & 15;
            pf[it] = *reinterpret_cast<const float4*>(xn + c * 500 + t4 * 4);
        }
    }
    #pragma unroll
    for (int it = 0; it < 4; ++it) {
        const int i = it * NTHREADS + tid;
        if (i < 1280) {
            const int c  = i >> 4;
            const int t4 = i & 15;
            *reinterpret_cast<float4*>(&xs[c * TC + t4 * 4]) = pf[it];
        }
    }
    __syncthreads();

    for (int chunk = 0; chunk < NCHUNK; ++chunk) {
        // ---- issue next chunk's global loads (completion hidden under FIR) ----
        if (chunk < NCHUNK - 1) {
            const int t0n = (chunk + 1) * TC;
            #pragma unroll
            for (int it = 0; it < 4; ++it) {
                const int i = it * NTHREADS + tid;
                if (i < 1280) {
                    const int c  = i >> 4;
                    const int t4 = i & 15;
                    int toff = t0n + t4 * 4;
                    if (toff > 496) toff = 496;   // tail clamp (cols 52..63 unused)
                    pf[it] = *reinterpret_cast<const float4*>(xn + c * 500 + toff);
                }
            }
        }

        // ---- register FIR: y[co0+r][lane] = sum_k w[k]*x[co0+r+k-32, lane] ----
        {
            float acc[CPW];
            float win[CPW];                 // win[(k+r)%CPW] = row co0+k+r-32
            #pragma unroll
            for (int r = 0; r < CPW; ++r) acc[r] = 0.0f;
            const int row0 = co0 - 32;
            #pragma unroll
            for (int m = 0; m < CPW - 1; ++m) {
                const int row = row0 + m;
                win[m] = ((unsigned)row < 80u) ? xs[row * TC + lane] : 0.0f;
            }
            #pragma unroll
            for (int k = 0; k < 64; ++k) {
                const int row = row0 + k + (CPW - 1);
                win[(k + CPW - 1) % CPW] =
                    ((unsigned)row < 80u) ? xs[row * TC + lane] : 0.0f;
                const float wk = wsh[k];                   // LDS broadcast
                #pragma unroll
                for (int r = 0; r < CPW; ++r)
                    acc[r] = fmaf(wk, win[(k + r) % CPW], acc[r]);
            }
            #pragma unroll
            for (int r = 0; r < CPW; ++r) {
                const int co = co0 + r;
                if (co < 81) ybuf[co * YSTRIDE + lane] = acc[r];
            }
        }
        __syncthreads();   // ybuf ready; all FIR reads of xs complete

        // ---- write next chunk into xs (overlaps scan; xs not read here) ----
        if (chunk < NCHUNK - 1) {
            #pragma unroll
            for (int it = 0; it < 4; ++it) {
                const int i = it * NTHREADS + tid;
                if (i < 1280) {
                    const int c  = i >> 4;
                    const int t4 = i & 15;
                    *reinterpret_cast<float4*>(&xs[c * TC + t4 * 4]) = pf[it];
                }
            }
        }

        // ---- PLIF scan: lane c advances tcols steps ----
        const int tcols = (chunk == NCHUNK - 1) ? 52 : 64;  // 500 = 7*64+52
        if (tid < 81) {
            const float* yrow = &ybuf[tid * YSTRIDE];
            #pragma unroll 4
            for (int t = 0; t < tcols; ++t) {
                const float xt = fmaf(yrow[t], inv_c, bb_c);   // BN(conv+bias)
                v = fmaf(xt - v, decay, v);                    // v += (x-v)*decay
                const bool s = (v >= 1.0f);
                cnt += s ? 1.0f : 0.0f;
                v = s ? 0.0f : v;
            }
        }
        __syncthreads();   // scan done reading ybuf; xs fully staged
    }

    if (tid < 81) feat[tid] = cnt * (1.0f / 500.0f);
    __syncthreads();

    if (tid < 3) {
        float o = fc_b[tid];
        #pragma unroll 3
        for (int c = 0; c < 81; ++c)
            o = fmaf(feat[c], fc_w[tid * 81 + c], o);
        out[n * 3 + tid] = o;
    }
}

extern "C" void kernel_launch(void* const* d_in, const int* in_sizes, int n_in,
                              void* d_out, int out_size, void* d_ws, size_t ws_size,
                              hipStream_t stream)
{
    const float* x        = (const float*)d_in[0];
    const float* conv_w   = (const float*)d_in[1];
    const float* conv_b   = (const float*)d_in[2];
    const float* bn_gamma = (const float*)d_in[3];
    const float* bn_beta  = (const float*)d_in[4];
    const float* bn_mean  = (const float*)d_in[5];
    const float* bn_var   = (const float*)d_in[6];
    const float* plif_w   = (const float*)d_in[7];
    const float* fc_w     = (const float*)d_in[8];
    const float* fc_b     = (const float*)d_in[9];
    float* out            = (float*)d_out;

    snn_fused_kernel<<<1024, NTHREADS, 0, stream>>>(
        x, conv_w, conv_b, bn_gamma, bn_beta, bn_mean, bn_var,
        plif_w, fc_w, fc_b, out);
}

// Round 5
// 191.395 us; speedup vs baseline: 1.4505x; 1.2584x over previous
//
#include <hip/hip_runtime.h>
#include <math.h>

// Fused SNN: conv1d(64-tap over C, pad 32) + BN + PLIF scan over T + mean + FC.
// x: (1024, 80, 500) f32. One block per sample n. 384 threads = 6 waves.
// Wave w owns channels co0=14*w..co0+13 (84 covers 81); CPW=14 is the proven
// full-unroll size (R3's 21 and R4's live-across-FIR prefetch both spilled).
// R5 structure per chunk (2 barriers):
//   FIR (reads xs) -> ybuf | bar | { scan: tid<81 reads ybuf  ||
//   stage next xs: tid>=128 global->LDS } | bar
// The stage phase rides in the scan's shadow using the 4 waves that were
// idle there; no registers live across the FIR -> no scratch.
// __launch_bounds__(384,8) caps VGPR at 64 -> 32-wave/CU bucket; LDS 42KB
// then admits 3 resident blocks (was 2) to hide per-block serial phases.

#define NTHREADS 384
#define CPW      14
#define TC       64
#define YSTRIDE  65       // +1 pad: conflict-free column reads in scan
#define NCHUNK   8        // 7*64 + 52 = 500

__global__ __launch_bounds__(NTHREADS, 8)
void snn_fused_kernel(const float* __restrict__ x,
                      const float* __restrict__ conv_w,
                      const float* __restrict__ conv_b,
                      const float* __restrict__ bn_gamma,
                      const float* __restrict__ bn_beta,
                      const float* __restrict__ bn_mean,
                      const float* __restrict__ bn_var,
                      const float* __restrict__ plif_w,
                      const float* __restrict__ fc_w,
                      const float* __restrict__ fc_b,
                      float* __restrict__ out)
{
    __shared__ float xs[80 * TC];          // 20480 B
    __shared__ float ybuf[81 * YSTRIDE];   // 21060 B
    __shared__ float wsh[64];
    __shared__ float feat[81];

    const int tid  = threadIdx.x;
    const int n    = blockIdx.x;
    const int lane = tid & 63;             // t column within chunk
    const int co0  = (tid >> 6) * CPW;     // wave's first output channel

    if (tid < 64) wsh[tid] = conv_w[tid];

    // per-lane scan constants (lanes 0..80 = channels)
    const float decay = 1.0f / (1.0f + expf(-plif_w[0]));
    float v = 0.0f, cnt = 0.0f;
    float inv_c = 0.0f, bb_c = 0.0f;
    if (tid < 81) {
        inv_c = bn_gamma[tid] * rsqrtf(bn_var[tid] + 1e-5f);
        bb_c  = conv_b[0] * inv_c + bn_beta[tid] - bn_mean[tid] * inv_c;
    }

    const float* xn = x + (size_t)n * (80 * 500);

    // ---- prologue: stage chunk 0 (80 rows x 16 float4 = 1280 items) ----
    for (int i = tid; i < 1280; i += NTHREADS) {
        const int c  = i >> 4;
        const int t4 = i & 15;
        float4 v4 = *reinterpret_cast<const float4*>(xn + c * 500 + t4 * 4);
        *reinterpret_cast<float4*>(&xs[c * TC + t4 * 4]) = v4;
    }
    __syncthreads();

    for (int chunk = 0; chunk < NCHUNK; ++chunk) {
        // ---- register FIR: y[co0+r][lane] = sum_k w[k]*x[co0+r+k-32, lane] ----
        {
            float acc[CPW];
            float win[CPW];                 // win[(k+r)%CPW] = row co0+k+r-32
            #pragma unroll
            for (int r = 0; r < CPW; ++r) acc[r] = 0.0f;
            const int row0 = co0 - 32;
            #pragma unroll
            for (int m = 0; m < CPW - 1; ++m) {
                const int row = row0 + m;
                win[m] = ((unsigned)row < 80u) ? xs[row * TC + lane] : 0.0f;
            }
            #pragma unroll
            for (int k = 0; k < 64; ++k) {
                const int row = row0 + k + (CPW - 1);
                win[(k + CPW - 1) % CPW] =
                    ((unsigned)row < 80u) ? xs[row * TC + lane] : 0.0f;
                const float wk = wsh[k];                   // LDS broadcast
                #pragma unroll
                for (int r = 0; r < CPW; ++r)
                    acc[r] = fmaf(wk, win[(k + r) % CPW], acc[r]);
            }
            #pragma unroll
            for (int r = 0; r < CPW; ++r) {
                const int co = co0 + r;
                if (co < 81) ybuf[co * YSTRIDE + lane] = acc[r];
            }
        }
        __syncthreads();   // ybuf ready; ALL xs reads complete

        // ---- overlap: PLIF scan (tid<81)  ||  stage next chunk (tid>=128) ----
        if (tid < 81) {
            const int tcols = (chunk == NCHUNK - 1) ? 52 : 64;  // 500 = 7*64+52
            const float* yrow = &ybuf[tid * YSTRIDE];
            #pragma unroll 4
            for (int t = 0; t < tcols; ++t) {
                const float xt = fmaf(yrow[t], inv_c, bb_c);   // BN(conv+bias)
                v = fmaf(xt - v, decay, v);                    // v += (x-v)*decay
                const bool s = (v >= 1.0f);
                cnt += s ? 1.0f : 0.0f;
                v = s ? 0.0f : v;
            }
        } else if (tid >= 128 && chunk < NCHUNK - 1) {
            // waves 2..5 (256 threads): 1280 items, 5 each, no guard
            const int t0n = (chunk + 1) * TC;
            const int b   = tid - 128;
            #pragma unroll
            for (int it = 0; it < 5; ++it) {
                const int i  = it * 256 + b;
                const int c  = i >> 4;
                const int t4 = i & 15;
                int toff = t0n + t4 * 4;
                if (toff > 496) toff = 496;   // tail clamp (cols 52..63 unused)
                float4 v4 = *reinterpret_cast<const float4*>(xn + c * 500 + toff);
                *reinterpret_cast<float4*>(&xs[c * TC + t4 * 4]) = v4;
            }
        }
        __syncthreads();   // scan done with ybuf; xs staged for next chunk
    }

    if (tid < 81) feat[tid] = cnt * (1.0f / 500.0f);
    __syncthreads();

    if (tid < 3) {
        float o = fc_b[tid];
        #pragma unroll 3
        for (int c = 0; c < 81; ++c)
            o = fmaf(feat[c], fc_w[tid * 81 + c], o);
        out[n * 3 + tid] = o;
    }
}

extern "C" void kernel_launch(void* const* d_in, const int* in_sizes, int n_in,
                              void* d_out, int out_size, void* d_ws, size_t ws_size,
                              hipStream_t stream)
{
    const float* x        = (const float*)d_in[0];
    const float* conv_w   = (const float*)d_in[1];
    const float* conv_b   = (const float*)d_in[2];
    const float* bn_gamma = (const float*)d_in[3];
    const float* bn_beta  = (const float*)d_in[4];
    const float* bn_mean  = (const float*)d_in[5];
    const float* bn_var   = (const float*)d_in[6];
    const float* plif_w   = (const float*)d_in[7];
    const float* fc_w     = (const float*)d_in[8];
    const float* fc_b     = (const float*)d_in[9];
    float* out            = (float*)d_out;

    snn_fused_kernel<<<1024, NTHREADS, 0, stream>>>(
        x, conv_w, conv_b, bn_gamma, bn_beta, bn_mean, bn_var,
        plif_w, fc_w, fc_b, out);
}